// Round 12
// baseline (1726.397 us; speedup 1.0000x reference)
//
#include <hip/hip_runtime.h>
#include <hip/hip_bf16.h>
#include <cstdint>

#define TSTEPS 512
#define BATCH  256
#define HID    512
#define INP    64
#define NGRP   16          // batch groups (16 rows each)
#define GROWS  16
#define NSL    16          // WG slices per group (32 hid cols each)
#define NWG    256
#define KTH    16          // h K-tiles (512/32)
#define RING   8           // h ring depth (stale-L1 eviction margin)

typedef __attribute__((ext_vector_type(8))) short short8;
typedef __attribute__((ext_vector_type(4))) float f32x4;
typedef __attribute__((ext_vector_type(2))) float f32x2;

// workspace layout
#define HB_OFF    0                            // RING x (BATCH*HID*2) h slots
#define HT_OFF    (RING*BATCH*HID*2)
#define FLAGS_OFF (HT_OFF + BATCH*HID*4)       // [16 grp][512 t] int counters (R10 style)
#define FLAGS_SZ  (NGRP*TSTEPS*4)
#define CNT_OFF   (FLAGS_OFF + FLAGS_SZ)
#define ZERO2_SZ  (FLAGS_SZ + 64)

__device__ __forceinline__ unsigned cvtpk(float a, float b) {
    unsigned r;
    asm("v_cvt_pk_bf16_f32 %0, %1, %2" : "=v"(r) : "v"(a), "v"(b));
    return r;   // low16 = bf16(a), high16 = bf16(b), RNE
}
__device__ __forceinline__ short8 pack8(float4 a0, float4 a1) {
    uint4 u = { cvtpk(a0.x, a0.y), cvtpk(a0.z, a0.w),
                cvtpk(a1.x, a1.y), cvtpk(a1.z, a1.w) };
    return __builtin_bit_cast(short8, u);
}
__device__ __forceinline__ float sigm(float x)  { return 1.0f/(1.0f + __expf(-x)); }
__device__ __forceinline__ float tanhf_(float x){ return 2.0f/(1.0f + __expf(-2.0f*x)) - 1.0f; }

__global__ void __launch_bounds__(256, 1)
lstm_persist(const float* __restrict__ x,   const float* __restrict__ Wih,
             const float* __restrict__ Whh, const float* __restrict__ bih,
             const float* __restrict__ bhh, const float* __restrict__ Whead,
             const float* __restrict__ bhead, float* __restrict__ out,
             char* __restrict__ ws)
{
    extern __shared__ char lds[];   // 128 KiB requested: forces 1 WG/CU (bijection); loop uses NONE
    const int tid  = threadIdx.x;
    const int lane = tid & 63;
    const int wv   = tid >> 6;
    const int l15  = lane & 15, lq = lane >> 4;

    unsigned short* hb = (unsigned short*)(ws + HB_OFF);
    float* hT  = (float*)(ws + HT_OFF);
    int* flags = (int*)(ws + FLAGS_OFF);
    int* cnt   = (int*)(ws + CNT_OFF);

    // ---- self-organize by XCD: 32 WGs/XCD (capacity-guaranteed) -> 2 groups x 16 slices ----
    int* org = (int*)(lds + 131056);
    if (tid == 0) {
        unsigned xcd;
        asm volatile("s_getreg_b32 %0, hwreg(HW_REG_XCC_ID)" : "=s"(xcd));
        xcd &= 7u;
        int slot = __hip_atomic_fetch_add(&cnt[xcd], 1, __ATOMIC_RELAXED, __HIP_MEMORY_SCOPE_AGENT) & 31;
        org[0] = (int)xcd * 2 + (slot >> 4);
        org[1] = slot & 15;
    }
    __syncthreads();
    const int g  = org[0];
    const int sl = org[1];
    const int hb8 = sl*32 + wv*8;          // wave's 8 hidden cols

    // ---- weights as MFMA *A* operand (R11-verified): lane l15 -> (hidloc=l15>>2, gate=l15&3)
    short8 whh[KTH][2];
    #pragma unroll
    for (int kt = 0; kt < KTH; ++kt)
        #pragma unroll
        for (int m = 0; m < 2; ++m) {
            int grow = (l15 & 3)*HID + hb8 + m*4 + (l15 >> 2);
            const float4* p = (const float4*)(Whh + (size_t)grow*HID + kt*32 + lq*8);
            whh[kt][m] = pack8(p[0], p[1]);
        }
    short8 wihf[2][2];
    #pragma unroll
    for (int kt = 0; kt < 2; ++kt)
        #pragma unroll
        for (int m = 0; m < 2; ++m) {
            int grow = (l15 & 3)*HID + hb8 + m*4 + (l15 >> 2);
            const float4* p = (const float4*)(Wih + (size_t)grow*INP + kt*32 + lq*8);
            wihf[kt][m] = pack8(p[0], p[1]);
        }
    // bias: acc_m[r] = gate r of hidcol hb8+m*4+lq, batchrow l15
    f32x4 bias[2];
    #pragma unroll
    for (int m = 0; m < 2; ++m)
        #pragma unroll
        for (int r = 0; r < 4; ++r) {
            int hc = hb8 + m*4 + lq;
            bias[m][r] = bih[r*HID + hc] + bhh[r*HID + hc];
        }

    unsigned short* hgrp = hb + (size_t)g*GROWS*HID;   // + slot*(BATCH*HID)
    float*          hTg  = hT + (size_t)g*GROWS*HID;
    int* flg = flags + g*TSTEPS;

    const float* xrow = x + ((size_t)(g*GROWS + l15)*TSTEPS)*INP + lq*8;  // B-frag: l15=batchrow

    f32x2 cst = {0.f, 0.f};

    // x prefetch for t=0
    float4 xv0 = *(const float4*)(xrow);
    float4 xv1 = *(const float4*)(xrow + 4);
    float4 xv2 = *(const float4*)(xrow + 32);
    float4 xv3 = *(const float4*)(xrow + 36);

    #pragma clang loop unroll(disable)
    for (int t = 0; t < TSTEPS; ++t) {
        // pack x B-frags (uses prior-step loads; off critical path)
        short8 bfx0 = pack8(xv0, xv1);
        short8 bfx1 = pack8(xv2, xv3);
        __builtin_amdgcn_sched_barrier(0);

        // single-lane poll per wave (R10-proven); waves proceed autonomously (no mid barrier)
        if (t) {
            if (lane == 0) {
                const int* fl = flg + (t-1);
                while (__hip_atomic_load(fl, __ATOMIC_RELAXED, __HIP_MEMORY_SCOPE_AGENT) < NSL) {}
            }
            __builtin_amdgcn_sched_barrier(0);
            asm volatile("" ::: "memory");
        }

        // direct-to-register B-frags: lane holds h[l15][kt*32+lq*8 ..+8], PLAIN cached loads.
        // 16 instrs/wave, 16 lines x 4 lanes each; waves share via L1 (post-flag => fresh);
        // ring-8 => stale lines structurally evicted (~168KB/8 steps >> 32KB L1).
        short8 hf[KTH];
        {
            const char* hsrc = (const char*)(hgrp + (size_t)(t & (RING-1))*BATCH*HID)
                               + l15*1024 + lq*16;
            #pragma unroll
            for (int kt = 0; kt < KTH; ++kt)
                hf[kt] = *(const short8*)(hsrc + kt*64);
        }
        // x loads for t+1: issued after h burst, drained at end-of-step barrier
        if (t + 1 < TSTEPS) {
            const float* xn = xrow + (size_t)(t+1)*INP;
            xv0 = *(const float4*)(xn);      xv1 = *(const float4*)(xn + 4);
            xv2 = *(const float4*)(xn + 32); xv3 = *(const float4*)(xn + 36);
        }

        // MFMA, weights as A: 4 independent chains; x-MFMAs first (overlap h-load latency)
        f32x4 a0 = bias[0], a1 = bias[1];
        f32x4 b0 = {0.f,0.f,0.f,0.f}, b1 = {0.f,0.f,0.f,0.f};
        a0 = __builtin_amdgcn_mfma_f32_16x16x32_bf16(wihf[0][0], bfx0, a0, 0, 0, 0);
        a1 = __builtin_amdgcn_mfma_f32_16x16x32_bf16(wihf[0][1], bfx0, a1, 0, 0, 0);
        b0 = __builtin_amdgcn_mfma_f32_16x16x32_bf16(wihf[1][0], bfx1, b0, 0, 0, 0);
        b1 = __builtin_amdgcn_mfma_f32_16x16x32_bf16(wihf[1][1], bfx1, b1, 0, 0, 0);
        #pragma unroll
        for (int k2 = 0; k2 < 8; ++k2) {
            a0 = __builtin_amdgcn_mfma_f32_16x16x32_bf16(whh[2*k2  ][0], hf[2*k2  ], a0, 0, 0, 0);
            a1 = __builtin_amdgcn_mfma_f32_16x16x32_bf16(whh[2*k2  ][1], hf[2*k2  ], a1, 0, 0, 0);
            b0 = __builtin_amdgcn_mfma_f32_16x16x32_bf16(whh[2*k2+1][0], hf[2*k2+1], b0, 0, 0, 0);
            b1 = __builtin_amdgcn_mfma_f32_16x16x32_bf16(whh[2*k2+1][1], hf[2*k2+1], b1, 0, 0, 0);
        }
        f32x4 acc0 = a0 + b0;
        f32x4 acc1 = a1 + b1;

        // shuffle-free epilogue (R11-verified): lane=batchrow l15; acc_m={i,f,g,o} of hidcol hb8+m*4+lq
        unsigned short* hbw = hgrp + (size_t)((t+1) & (RING-1))*BATCH*HID;
        #pragma unroll
        for (int m = 0; m < 2; ++m) {
            f32x4 A = m ? acc1 : acc0;
            float c = sigm(A[1])*cst[m] + sigm(A[0])*tanhf_(A[2]);
            cst[m] = c;
            float h = sigm(A[3])*tanhf_(c);
            int idx = l15*HID + hb8 + m*4 + lq;
            hbw[idx] = (unsigned short)(cvtpk(h, h) & 0xffffu);
            if (t == TSTEPS-1) hTg[idx] = h;
        }
        __syncthreads();   // the ONLY barrier: vmcnt(0) drains h stores (and x prefetch) -> publish
        if (tid == 0)
            __hip_atomic_fetch_add(&flg[t], 1, __ATOMIC_RELAXED, __HIP_MEMORY_SCOPE_AGENT);
    }

    // ---- heads: slice-0 WG of each group ----
    if (sl == 0) {
        if (tid == 0) {
            const int* fl = flg + (TSTEPS-1);
            while (__hip_atomic_load(fl, __ATOMIC_RELAXED, __HIP_MEMORY_SCOPE_AGENT) < NSL) {}
        }
        asm volatile("" ::: "memory");
        __syncthreads();
        // stage hT tile (16x512 f32 = 32 KiB) into LDS; never read before by this WG
        {
            const float4* gp = (const float4*)((const char*)hTg + tid*128);
            float4* wp = (float4*)(lds + tid*128);
            #pragma unroll
            for (int j = 0; j < 8; ++j) wp[j] = gp[j];
        }
        __syncthreads();
        const float* hsm = (const float*)lds;
        for (int idx = tid; idx < 6*GROWS*3; idx += 256) {
            int k = idx / (GROWS*3), rem = idx % (GROWS*3);
            int row = rem / 3, o = rem % 3;
            const float* wp = Whead + ((size_t)k*3 + o)*HID;
            const float* hp = hsm + row*HID;
            float s = 0.f;
            for (int hh = 0; hh < HID; hh += 4) {
                float4 hv = *(const float4*)(hp + hh);
                float4 wv2 = *(const float4*)(wp + hh);
                s += hv.x*wv2.x + hv.y*wv2.y + hv.z*wv2.z + hv.w*wv2.w;
            }
            out[((size_t)k*BATCH + g*GROWS + row)*3 + o] = s + bhead[k*3 + o];
        }
    }
}

extern "C" void kernel_launch(void* const* d_in, const int* in_sizes, int n_in,
                              void* d_out, int out_size, void* d_ws, size_t ws_size,
                              hipStream_t stream) {
    (void)in_sizes; (void)n_in; (void)out_size; (void)ws_size;
    const float* x     = (const float*)d_in[0];
    const float* Wih   = (const float*)d_in[1];
    const float* Whh   = (const float*)d_in[2];
    const float* bih   = (const float*)d_in[3];
    const float* bhh   = (const float*)d_in[4];
    const float* Whead = (const float*)d_in[5];
    const float* bhead = (const float*)d_in[6];
    char* ws = (char*)d_ws;

    (void)hipFuncSetAttribute((const void*)lstm_persist,
                              hipFuncAttributeMaxDynamicSharedMemorySize, 131072);

    // per-launch reset: h_0 slot 0 = 0, flags = 0, xcd slot counters = 0
    (void)hipMemsetAsync(ws + HB_OFF, 0, BATCH*HID*2, stream);
    (void)hipMemsetAsync(ws + FLAGS_OFF, 0, ZERO2_SZ, stream);

    hipLaunchKernelGGL(lstm_persist, dim3(NWG), dim3(256), 131072, stream,
                       x, Wih, Whh, bih, bhh, Whead, bhead, (float*)d_out, ws);
}

// Round 13
// 1005.513 us; speedup vs baseline: 1.7169x; 1.7169x over previous
//
#include <hip/hip_runtime.h>
#include <hip/hip_bf16.h>
#include <cstdint>

#define TSTEPS 512
#define BATCH  256
#define HID    512
#define INP    64
#define NGRP   16          // batch groups (16 rows each)
#define GROWS  16
#define NSL    16          // WG slices per group (32 hid cols each)
#define NWG    256
#define KTH    16          // h K-tiles (512/32)
#define RING   8           // h ring depth (stale-L1 eviction margin)

typedef __attribute__((ext_vector_type(8))) short short8;
typedef __attribute__((ext_vector_type(4))) float f32x4;
typedef __attribute__((ext_vector_type(2))) float f32x2;
typedef __attribute__((ext_vector_type(2))) unsigned long long ull2;

// workspace layout
#define HB_OFF    0                            // RING x (BATCH*HID*2) h slots
#define HT_OFF    (RING*BATCH*HID*2)
#define FLAGS_OFF (HT_OFF + BATCH*HID*4)       // [16 grp][16 producer] x 64B lines
#define FLAGS_SZ  (NGRP*NSL*64)
#define CNT_OFF   (FLAGS_OFF + FLAGS_SZ)
#define ZERO2_SZ  (FLAGS_SZ + 64)

__device__ __forceinline__ unsigned cvtpk(float a, float b) {
    unsigned r;
    asm("v_cvt_pk_bf16_f32 %0, %1, %2" : "=v"(r) : "v"(a), "v"(b));
    return r;   // low16 = bf16(a), high16 = bf16(b), RNE
}
__device__ __forceinline__ short8 pack8(float4 a0, float4 a1) {
    uint4 u = { cvtpk(a0.x, a0.y), cvtpk(a0.z, a0.w),
                cvtpk(a1.x, a1.y), cvtpk(a1.z, a1.w) };
    return __builtin_bit_cast(short8, u);
}
__device__ __forceinline__ float sigm(float x)  { return 1.0f/(1.0f + __expf(-x)); }
__device__ __forceinline__ float tanhf_(float x){ return 2.0f/(1.0f + __expf(-2.0f*x)) - 1.0f; }

__global__ void __launch_bounds__(256, 1)
lstm_persist(const float* __restrict__ x,   const float* __restrict__ Wih,
             const float* __restrict__ Whh, const float* __restrict__ bih,
             const float* __restrict__ bhh, const float* __restrict__ Whead,
             const float* __restrict__ bhead, float* __restrict__ out,
             char* __restrict__ ws)
{
    extern __shared__ char lds[];   // 128 KiB requested (forces 1 WG/CU); 16 KiB stage
    const int tid  = threadIdx.x;
    const int lane = tid & 63;
    const int wv   = tid >> 6;
    const int l15  = lane & 15, lq = lane >> 4;

    unsigned short* hb = (unsigned short*)(ws + HB_OFF);
    float* hT  = (float*)(ws + HT_OFF);
    unsigned* flags = (unsigned*)(ws + FLAGS_OFF);
    int* cnt   = (int*)(ws + CNT_OFF);

    // ---- self-organize by XCD: 32 WGs/XCD (capacity-guaranteed) -> 2 groups x 16 slices ----
    // keeps ALL h traffic within one XCD's L2 (why plain cached loads are coherent here)
    int* org = (int*)(lds + 131056);
    if (tid == 0) {
        unsigned xcd;
        asm volatile("s_getreg_b32 %0, hwreg(HW_REG_XCC_ID)" : "=s"(xcd));
        xcd &= 7u;
        int slot = __hip_atomic_fetch_add(&cnt[xcd], 1, __ATOMIC_RELAXED, __HIP_MEMORY_SCOPE_AGENT) & 31;
        org[0] = (int)xcd * 2 + (slot >> 4);
        org[1] = slot & 15;
    }
    __syncthreads();
    const int g  = org[0];
    const int sl = org[1];
    const int hb8 = sl*32 + wv*8;          // wave's 8 hidden cols

    // ---- weights as MFMA *A* operand (R11/R12-verified): lane l15 -> (hidloc=l15>>2, gate=l15&3)
    short8 whh[KTH][2];
    #pragma unroll
    for (int kt = 0; kt < KTH; ++kt)
        #pragma unroll
        for (int m = 0; m < 2; ++m) {
            int grow = (l15 & 3)*HID + hb8 + m*4 + (l15 >> 2);
            const float4* p = (const float4*)(Whh + (size_t)grow*HID + kt*32 + lq*8);
            whh[kt][m] = pack8(p[0], p[1]);
        }
    short8 wihf[2][2];
    #pragma unroll
    for (int kt = 0; kt < 2; ++kt)
        #pragma unroll
        for (int m = 0; m < 2; ++m) {
            int grow = (l15 & 3)*HID + hb8 + m*4 + (l15 >> 2);
            const float4* p = (const float4*)(Wih + (size_t)grow*INP + kt*32 + lq*8);
            wihf[kt][m] = pack8(p[0], p[1]);
        }
    f32x4 bias[2];
    #pragma unroll
    for (int m = 0; m < 2; ++m)
        #pragma unroll
        for (int r = 0; r < 4; ++r) {
            int hc = hb8 + m*4 + lq;
            bias[m][r] = bih[r*HID + hc] + bhh[r*HID + hc];
        }

    unsigned short* hgrp = hb + (size_t)g*GROWS*HID;   // + slot*(BATCH*HID)
    float*          hTg  = hT + (size_t)g*GROWS*HID;

    // per-producer flag lines (64B apart), monotonic value t+1, single-writer
    unsigned* flg  = flags + (size_t)g*NSL*16;
    unsigned* fpub = flg + sl*16;
    const unsigned* fpoll = flg + (4*wv + lq)*16;  // wave wv's l15==0 lanes poll producers 4wv..4wv+3

    // staging map (R10 proven): thread (skt=tid>>4, sr=tid&15) stages 64B of producer skt
    const int skt = tid >> 4, sr = tid & 15;
    char* swp = lds + skt*1024 + sr*16;            // + s*256 for k-sub-block s=0..3
    const char* srp = lds + lane*16;               // B-frag read: + kt*1024 (conflict-free)

    const float* xrow = x + ((size_t)(g*GROWS + l15)*TSTEPS)*INP + lq*8;  // B-frag: l15=batchrow

    f32x2 cst = {0.f, 0.f};

    // x prefetch for t=0
    float4 xv0 = *(const float4*)(xrow);
    float4 xv1 = *(const float4*)(xrow + 4);
    float4 xv2 = *(const float4*)(xrow + 32);
    float4 xv3 = *(const float4*)(xrow + 36);

    #pragma clang loop unroll(disable)
    for (int t = 0; t < TSTEPS; ++t) {
        // x-part: pack + 4 MFMAs on 4 independent chains (pre-poll, off critical path)
        short8 bfx0 = pack8(xv0, xv1);
        short8 bfx1 = pack8(xv2, xv3);
        f32x4 a0 = bias[0], a1 = bias[1];
        f32x4 b0 = {0.f,0.f,0.f,0.f}, b1 = {0.f,0.f,0.f,0.f};
        a0 = __builtin_amdgcn_mfma_f32_16x16x32_bf16(wihf[0][0], bfx0, a0, 0, 0, 0);
        a1 = __builtin_amdgcn_mfma_f32_16x16x32_bf16(wihf[0][1], bfx0, a1, 0, 0, 0);
        b0 = __builtin_amdgcn_mfma_f32_16x16x32_bf16(wihf[1][0], bfx1, b0, 0, 0, 0);
        b1 = __builtin_amdgcn_mfma_f32_16x16x32_bf16(wihf[1][1], bfx1, b1, 0, 0, 0);
        __builtin_amdgcn_sched_barrier(0);

        // partial-order poll: wave waits only for the 4 producers it stages
        // (4 lanes l15==0, each its own single-writer line; exec-mask holds the wave)
        if (t) {
            if (l15 == 0) {
                while (__hip_atomic_load(fpoll, __ATOMIC_RELAXED, __HIP_MEMORY_SCOPE_AGENT)
                       < (unsigned)t) {}
            }
            __builtin_amdgcn_sched_barrier(0);
            asm volatile("" ::: "memory");
        }

        // stage h_{t-1} (slot t&7) into LDS via plain cached loads (same-XCD L2)
        {
            const char* gsrc = (const char*)(hgrp + (size_t)(t & (RING-1))*BATCH*HID)
                               + sr*1024 + skt*64;
            ull2 w0 = *(const ull2*)(gsrc);
            ull2 w1 = *(const ull2*)(gsrc + 16);
            ull2 w2 = *(const ull2*)(gsrc + 32);
            ull2 w3 = *(const ull2*)(gsrc + 48);
            *(ull2*)(swp      ) = w0;
            *(ull2*)(swp + 256) = w1;
            *(ull2*)(swp + 512) = w2;
            *(ull2*)(swp + 768) = w3;
        }
        __syncthreads();   // all-16 join happens here (after stage loads already issued)

        // x loads for t+1: drained at end-of-step barrier, hidden under MFMA+epilogue
        if (t + 1 < TSTEPS) {
            const float* xn = xrow + (size_t)(t+1)*INP;
            xv0 = *(const float4*)(xn);      xv1 = *(const float4*)(xn + 4);
            xv2 = *(const float4*)(xn + 32); xv3 = *(const float4*)(xn + 36);
        }

        // h-MFMAs, weights as A / staged h as B: even kt -> a-chains, odd -> b-chains
        #pragma unroll
        for (int k2 = 0; k2 < 8; ++k2) {
            short8 be = *(const short8*)(srp + (2*k2  )*1024);
            short8 bo = *(const short8*)(srp + (2*k2+1)*1024);
            a0 = __builtin_amdgcn_mfma_f32_16x16x32_bf16(whh[2*k2  ][0], be, a0, 0, 0, 0);
            a1 = __builtin_amdgcn_mfma_f32_16x16x32_bf16(whh[2*k2  ][1], be, a1, 0, 0, 0);
            b0 = __builtin_amdgcn_mfma_f32_16x16x32_bf16(whh[2*k2+1][0], bo, b0, 0, 0, 0);
            b1 = __builtin_amdgcn_mfma_f32_16x16x32_bf16(whh[2*k2+1][1], bo, b1, 0, 0, 0);
        }
        f32x4 acc0 = a0 + b0;
        f32x4 acc1 = a1 + b1;

        // shuffle-free epilogue (verified): lane=batchrow l15; acc_m={i,f,g,o} of hidcol hb8+m*4+lq
        unsigned short* hbw = hgrp + (size_t)((t+1) & (RING-1))*BATCH*HID;
        #pragma unroll
        for (int m = 0; m < 2; ++m) {
            f32x4 A = m ? acc1 : acc0;
            float c = sigm(A[1])*cst[m] + sigm(A[0])*tanhf_(A[2]);
            cst[m] = c;
            float h = sigm(A[3])*tanhf_(c);
            int idx = l15*HID + hb8 + m*4 + lq;
            hbw[idx] = (unsigned short)(cvtpk(h, h) & 0xffffu);
            if (t == TSTEPS-1) hTg[idx] = h;
        }
        __syncthreads();   // implicit vmcnt(0): all 4 waves' h stores in L2 -> publish
        if (tid == 0)
            __hip_atomic_store(fpub, (unsigned)(t+1),
                               __ATOMIC_RELAXED, __HIP_MEMORY_SCOPE_AGENT);
    }

    // ---- heads: slice-0 WG of each group ----
    if (sl == 0) {
        {
            unsigned v;
            do {
                v = (lane < NSL)
                    ? __hip_atomic_load(flg + lane*16, __ATOMIC_RELAXED, __HIP_MEMORY_SCOPE_AGENT)
                    : (unsigned)TSTEPS;
            } while (!__all(v >= (unsigned)TSTEPS));
            asm volatile("" ::: "memory");
        }
        __syncthreads();
        // stage hT tile (16x512 f32 = 32 KiB) into LDS; never read before by this WG
        {
            const float4* gp = (const float4*)((const char*)hTg + tid*128);
            float4* wp = (float4*)(lds + tid*128);
            #pragma unroll
            for (int j = 0; j < 8; ++j) wp[j] = gp[j];
        }
        __syncthreads();
        const float* hsm = (const float*)lds;
        for (int idx = tid; idx < 6*GROWS*3; idx += 256) {
            int k = idx / (GROWS*3), rem = idx % (GROWS*3);
            int row = rem / 3, o = rem % 3;
            const float* wp = Whead + ((size_t)k*3 + o)*HID;
            const float* hp = hsm + row*HID;
            float s = 0.f;
            for (int hh = 0; hh < HID; hh += 4) {
                float4 hv = *(const float4*)(hp + hh);
                float4 wv2 = *(const float4*)(wp + hh);
                s += hv.x*wv2.x + hv.y*wv2.y + hv.z*wv2.z + hv.w*wv2.w;
            }
            out[((size_t)k*BATCH + g*GROWS + row)*3 + o] = s + bhead[k*3 + o];
        }
    }
}

extern "C" void kernel_launch(void* const* d_in, const int* in_sizes, int n_in,
                              void* d_out, int out_size, void* d_ws, size_t ws_size,
                              hipStream_t stream) {
    (void)in_sizes; (void)n_in; (void)out_size; (void)ws_size;
    const float* x     = (const float*)d_in[0];
    const float* Wih   = (const float*)d_in[1];
    const float* Whh   = (const float*)d_in[2];
    const float* bih   = (const float*)d_in[3];
    const float* bhh   = (const float*)d_in[4];
    const float* Whead = (const float*)d_in[5];
    const float* bhead = (const float*)d_in[6];
    char* ws = (char*)d_ws;

    (void)hipFuncSetAttribute((const void*)lstm_persist,
                              hipFuncAttributeMaxDynamicSharedMemorySize, 131072);

    // per-launch reset: h_0 slot 0 = 0, flags = 0, xcd slot counters = 0
    (void)hipMemsetAsync(ws + HB_OFF, 0, BATCH*HID*2, stream);
    (void)hipMemsetAsync(ws + FLAGS_OFF, 0, ZERO2_SZ, stream);

    hipLaunchKernelGGL(lstm_persist, dim3(NWG), dim3(256), 131072, stream,
                       x, Wih, Whh, bih, bhh, Whead, bhead, (float*)d_out, ws);
}